// Round 12
// baseline (68.086 us; speedup 1.0000x reference)
//
#include <hip/hip_runtime.h>

// ResNetVQC: 6 q3-layers of 32 three-qubit circuits + linear head.
// Each (layer,block,wire) expectation is an exact trilinear form, factorized as
//   z_w = sum_p v0[p] * ( T[w][p][.] . m[.] ),
//   m = (1, c1, s1, c2, s2, c1c2, c1s2, s1c2, s1s2),  v0 = (1, c0, s0)
// evaluated with v_dot2_f32_f16 (T f16, f32 accumulate). T pre-scaled by 1/2pi
// (layers 0-4) so angles flow in REVOLUTIONS -> raw hw v_sin/v_cos.
//
// Round-12 change (math identical to round 11): T comes from LDS, not s_load.
//  * Hypothesis: the invariant ~18us stall is SGPR-starved just-in-time s_load
//    bursts inside the dot2 chains (64 SGPRs can't hold a layer's 192 T dwords
//    per wave). Fix: double-buffered per-layer T slice (6KB) in LDS.
//  * Prefetch: during layer l each thread loads 3 dwords of layer l+1's T to
//    registers (issue-early), ds_writes them right before the existing
//    end-of-layer barrier (write-late) -> latency hidden, zero new barriers.
//  * Evals read T wave-uniform from LDS: ds_read_b128 broadcast (conflict-free),
//    hf8 vector loads + free subregister shuffles -> v_dot2 with VGPR operands.
//  * Exchange: round-11 double-buffered f16 consumer-order buffer, 6 barriers.

#define INV2PI 0.15915494309189535f

typedef _Float16 hf2 __attribute__((ext_vector_type(2)));
typedef _Float16 hf4 __attribute__((ext_vector_type(4)));
typedef _Float16 hf8 __attribute__((ext_vector_type(8)));

#if __has_builtin(__builtin_amdgcn_fdot2)
#define HAVE_FDOT2 1
#else
#define HAVE_FDOT2 0
#endif

__device__ __forceinline__ float fdot2e(hf2 a, hf2 m, float acc) {
#if HAVE_FDOT2
  return __builtin_amdgcn_fdot2(a, m, acc, false);
#else
  return fmaf((float)a.x, (float)m.x, fmaf((float)a.y, (float)m.y, acc));
#endif
}

#if __has_builtin(__builtin_amdgcn_sinf)
__device__ __forceinline__ float hwsin(float r) { return __builtin_amdgcn_sinf(r); }
__device__ __forceinline__ float hwcos(float r) { return __builtin_amdgcn_cosf(r); }
#else
__device__ __forceinline__ float hwsin(float r) { return __sinf(r * 6.2831853071795865f); }
__device__ __forceinline__ float hwcos(float r) { return __cosf(r * 6.2831853071795865f); }
#endif

// ---------------- setup kernel: build T from thetas (identical to r11) -------
__global__ __launch_bounds__(256) void build_T(const float* __restrict__ thetas,
                                               hf2* __restrict__ Thp,
                                               hf2* __restrict__ T5) {
  __shared__ float Ur[32][8][8];  // [k][col][amp]
  __shared__ float Ui[32][8][8];
  const int l = blockIdx.x;
  const int t = threadIdx.x;
  const int k = t >> 3;
  const int col = t & 7;

  float pr[8], pi[8];
#pragma unroll
  for (int j = 0; j < 8; ++j) { pr[j] = (j == col) ? 1.f : 0.f; pi[j] = 0.f; }

  const float* th = thetas + (size_t)(l * 32 + k) * 54;  // [d][w][3]
#pragma unroll
  for (int d = 0; d < 6; ++d) {
#pragma unroll
    for (int w = 0; w < 3; ++w) {
      float phi = th[(d * 3 + w) * 3 + 0];
      float tht = th[(d * 3 + w) * 3 + 1];
      float omg = th[(d * 3 + w) * 3 + 2];
      float st, ct, sp, cp, sm, cm;
      __sincosf(0.5f * tht, &st, &ct);
      __sincosf(0.5f * (phi + omg), &sp, &cp);
      __sincosf(0.5f * (phi - omg), &sm, &cm);
      float m00r =  cp * ct, m00i = -sp * ct;
      float m01r = -cm * st, m01i = -sm * st;
      float m10r =  cm * st, m10i = -sm * st;
      float m11r =  cp * ct, m11i =  sp * ct;
      const int s = 4 >> w;  // qubit0 = MSB
#pragma unroll
      for (int base = 0; base < 8; ++base) {
        if (base & s) continue;
        float ar = pr[base], ai = pi[base];
        float br = pr[base + s], bi = pi[base + s];
        pr[base]     = m00r * ar - m00i * ai + m01r * br - m01i * bi;
        pi[base]     = m00r * ai + m00i * ar + m01r * bi + m01i * br;
        pr[base + s] = m10r * ar - m10i * ai + m11r * br - m11i * bi;
        pi[base + s] = m10r * ai + m10i * ar + m11r * bi + m11i * br;
      }
    }
    const int r = (d & 1) + 1;  // CNOT ring range: 1,2,1,2,...
#pragma unroll
    for (int w = 0; w < 3; ++w) {
      const int cs = 4 >> w;
      const int ts = 4 >> ((w + r) % 3);
#pragma unroll
      for (int idx = 0; idx < 8; ++idx) {
        if (!(idx & cs) || (idx & ts)) continue;
        const int j2 = idx | ts;
        float tr = pr[idx]; pr[idx] = pr[j2]; pr[j2] = tr;
        float ti = pi[idx]; pi[idx] = pi[j2]; pi[j2] = ti;
      }
    }
  }
#pragma unroll
  for (int j = 0; j < 8; ++j) { Ur[k][col][j] = pr[j]; Ui[k][col][j] = pi[j]; }
  __syncthreads();

  if (col < 3) {
    const int w = col;  // wire
    float rem[8][8];
#pragma unroll
    for (int a = 0; a < 8; ++a) {
#pragma unroll
      for (int bb = 0; bb < 8; ++bb) {
        float acc = 0.f;
#pragma unroll
        for (int c = 0; c < 8; ++c) {
          float zs = ((c >> (2 - w)) & 1) ? -1.f : 1.f;
          acc += zs * (Ur[k][a][c] * Ur[k][bb][c] + Ui[k][a][c] * Ui[k][bb][c]);
        }
        rem[a][bb] = acc;
      }
    }
    const int   ga[3][2] = {{0, 1}, {0, 1}, {0, 1}};
    const int   gb[3][2] = {{0, 1}, {0, 1}, {1, 0}};
    const float gc[3][2] = {{0.5f, 0.5f}, {0.5f, -0.5f}, {0.5f, 0.5f}};
    // monomial index for (q,r): m = (1,c1,s1,c2,s2,c1c2,c1s2,s1c2,s1s2)
    const int MONO[3][3] = {{0, 3, 4}, {1, 5, 6}, {2, 7, 8}};
    float tv[27];
#pragma unroll
    for (int p = 0; p < 3; ++p) {
#pragma unroll
      for (int q = 0; q < 3; ++q) {
#pragma unroll
        for (int rr = 0; rr < 3; ++rr) {
          float acc = 0.f;
#pragma unroll
          for (int e0 = 0; e0 < 2; ++e0)
#pragma unroll
            for (int e1 = 0; e1 < 2; ++e1)
#pragma unroll
              for (int e2 = 0; e2 < 2; ++e2) {
                int a  = (ga[p][e0] << 2) | (ga[q][e1] << 1) | ga[rr][e2];
                int bb = (gb[p][e0] << 2) | (gb[q][e1] << 1) | gb[rr][e2];
                acc += gc[p][e0] * gc[q][e1] * gc[rr][e2] * rem[a][bb];
              }
          tv[p * 9 + MONO[q][rr]] = acc;
        }
      }
    }
    // layers 0-4: scale by 1/2pi (outputs in revolutions, feeds raw v_sin)
    if (l < 5) {
#pragma unroll
      for (int i = 0; i < 27; ++i) tv[i] *= INV2PI;
      hf2* Tp = Thp + ((size_t)(l * 32 + k)) * 48 + w * 16;
#pragma unroll
      for (int p = 0; p < 3; ++p) {
#pragma unroll
        for (int d = 0; d < 4; ++d) {
          hf2 v = {(_Float16)tv[p * 9 + 2 * d], (_Float16)tv[p * 9 + 2 * d + 1]};
          Tp[p * 5 + d] = v;
        }
        hf2 v4 = {(_Float16)tv[p * 9 + 8], (_Float16)0.f};
        Tp[p * 5 + 4] = v4;
      }
      hf2 zz = {(_Float16)0.f, (_Float16)0.f};
      Tp[15] = zz;
    } else if (w == 0) {
      // layer 5 unscaled (its output feeds the classifier directly)
      hf2* Tp = T5 + k * 16;
#pragma unroll
      for (int p = 0; p < 3; ++p) {
#pragma unroll
        for (int d = 0; d < 4; ++d) {
          hf2 v = {(_Float16)tv[p * 9 + 2 * d], (_Float16)tv[p * 9 + 2 * d + 1]};
          Tp[p * 5 + d] = v;
        }
        hf2 v4 = {(_Float16)tv[p * 9 + 8], (_Float16)0.f};
        Tp[p * 5 + 4] = v4;
      }
      hf2 zz = {(_Float16)0.f, (_Float16)0.f};
      Tp[15] = zz;
    }
  }
}

// ---------------- main kernel evals ----------------
// eval for one k, 3 wires; T from a 48-dword LDS block via hf8 vector reads.
__device__ __forceinline__ void evalk(const unsigned int* __restrict__ tkd,
                                      float a0, float a1, float a2,
                                      float* __restrict__ z) {
  float s0 = hwsin(a0), c0 = hwcos(a0);
  float s1 = hwsin(a1), c1 = hwcos(a1);
  float s2 = hwsin(a2), c2 = hwcos(a2);
  float m5 = c1 * c2, m6 = c1 * s2, m7 = s1 * c2, m8 = s1 * s2;
  hf2 M0 = {(_Float16)1.0f, (_Float16)c1};
  hf2 M1 = {(_Float16)s1,   (_Float16)c2};
  hf2 M2 = {(_Float16)s2,   (_Float16)m5};
  hf2 M3 = {(_Float16)m6,   (_Float16)m7};
  hf2 M4 = {(_Float16)m8,   (_Float16)0.0f};
#pragma unroll
  for (int w = 0; w < 3; ++w) {
    const hf8* tv = (const hf8*)(tkd + w * 16);  // 16B-aligned
    hf8 A = tv[0], B = tv[1], C = tv[2], D = tv[3];
    // dword n = p*5+d of this wire; hf2 = elems (2*(n&3), +1) of vec n>>2
    hf2 t00 = __builtin_shufflevector(A, A, 0, 1);
    hf2 t01 = __builtin_shufflevector(A, A, 2, 3);
    hf2 t02 = __builtin_shufflevector(A, A, 4, 5);
    hf2 t03 = __builtin_shufflevector(A, A, 6, 7);
    hf2 t04 = __builtin_shufflevector(B, B, 0, 1);
    hf2 t10 = __builtin_shufflevector(B, B, 2, 3);
    hf2 t11 = __builtin_shufflevector(B, B, 4, 5);
    hf2 t12 = __builtin_shufflevector(B, B, 6, 7);
    hf2 t13 = __builtin_shufflevector(C, C, 0, 1);
    hf2 t14 = __builtin_shufflevector(C, C, 2, 3);
    hf2 t20 = __builtin_shufflevector(C, C, 4, 5);
    hf2 t21 = __builtin_shufflevector(C, C, 6, 7);
    hf2 t22 = __builtin_shufflevector(D, D, 0, 1);
    hf2 t23 = __builtin_shufflevector(D, D, 2, 3);
    hf2 t24 = __builtin_shufflevector(D, D, 4, 5);
    float P0 = fdot2e(t00, M0, 0.0f);
    P0 = fdot2e(t01, M1, P0);
    P0 = fdot2e(t02, M2, P0);
    P0 = fdot2e(t03, M3, P0);
    P0 = fdot2e(t04, M4, P0);
    float P1 = fdot2e(t10, M0, 0.0f);
    P1 = fdot2e(t11, M1, P1);
    P1 = fdot2e(t12, M2, P1);
    P1 = fdot2e(t13, M3, P1);
    P1 = fdot2e(t14, M4, P1);
    float P2 = fdot2e(t20, M0, 0.0f);
    P2 = fdot2e(t21, M1, P2);
    P2 = fdot2e(t22, M2, P2);
    P2 = fdot2e(t23, M3, P2);
    P2 = fdot2e(t24, M4, P2);
    z[w] = fmaf(s0, P2, fmaf(c0, P1, P0));
  }
}

// wire-0-only eval (layer 5); tb = 16 hf2 from GLOBAL (wave-uniform s_load).
__device__ __forceinline__ float evalk1(const hf2* __restrict__ tb,
                                        float a0, float a1, float a2) {
  float s0 = hwsin(a0), c0 = hwcos(a0);
  float s1 = hwsin(a1), c1 = hwcos(a1);
  float s2 = hwsin(a2), c2 = hwcos(a2);
  float m5 = c1 * c2, m6 = c1 * s2, m7 = s1 * c2, m8 = s1 * s2;
  hf2 M0 = {(_Float16)1.0f, (_Float16)c1};
  hf2 M1 = {(_Float16)s1,   (_Float16)c2};
  hf2 M2 = {(_Float16)s2,   (_Float16)m5};
  hf2 M3 = {(_Float16)m6,   (_Float16)m7};
  hf2 M4 = {(_Float16)m8,   (_Float16)0.0f};
  float P[3];
#pragma unroll
  for (int p = 0; p < 3; ++p) {
    const hf2* tt = tb + p * 5;
    float acc = fdot2e(tt[0], M0, 0.0f);
    acc = fdot2e(tt[1], M1, acc);
    acc = fdot2e(tt[2], M2, acc);
    acc = fdot2e(tt[3], M3, acc);
    acc = fdot2e(tt[4], M4, acc);
    P[p] = acc;
  }
  return fmaf(s0, P[2], fmaf(c0, P[1], P[0]));
}

// 512 threads = 8 waves; lane b = batch row (64/block); wave ws owns
// k in {4ws..4ws+3}. Exchange: double-buffered f16 buf[2][64][96] in
// consumer-order slots (one barrier per layer). T: double-buffered per-layer
// 1536-dword LDS slice, prefetched issue-early/write-late each layer.
__global__ __launch_bounds__(512, 8) void vqc_main(const float* __restrict__ x,
                                                   const hf2* __restrict__ Thp,
                                                   const hf2* __restrict__ T5,
                                                   const float* __restrict__ wcls,
                                                   const float* __restrict__ bcls,
                                                   float* __restrict__ out) {
  __shared__ __align__(16) _Float16 buf[2][64][96];     // 24576 B
  __shared__ __align__(16) unsigned int Tlds[2][1536];  // 12288 B
  const int t = threadIdx.x;
  const int b = t & 63;                                   // batch row in block
  const int ws = __builtin_amdgcn_readfirstlane(t >> 6);  // wave id 0..7 (scalar)
  const size_t b0 = (size_t)blockIdx.x * 64;
  const unsigned int* Tg = (const unsigned int*)Thp;      // dword view; layer stride 1536

  // prologue: issue layer-0 T loads + x loads, then write both to LDS
  unsigned int p0 = Tg[t], p1 = Tg[t + 512], p2 = Tg[t + 1024];
  const float4* xv = (const float4*)(x + b0 * 96);
#pragma unroll
  for (int i = 0; i < 3; ++i) {
    int f = t + i * 512;  // float4 index in 64x96 tile
    float4 v = xv[f];
    int d = 4 * f;
    int row = d / 96, col = d % 96;
    hf4 sv = {(_Float16)(v.x * INV2PI), (_Float16)(v.y * INV2PI),
              (_Float16)(v.z * INV2PI), (_Float16)(v.w * INV2PI)};
    *(hf4*)&buf[0][row][col] = sv;
  }
  Tlds[0][t] = p0; Tlds[0][t + 512] = p1; Tlds[0][t + 1024] = p2;
  __syncthreads();

  float h[4][3];

  // layers 0..4: read buf[l&1] + Tlds[l&1]; prefetch T l+1; write buf/Tlds ^1
#pragma unroll
  for (int l = 0; l < 5; ++l) {
    const int cur = l & 1;
    // issue next layer's T loads EARLY (latency hides under this layer's compute)
    unsigned int q0 = 0, q1 = 0, q2 = 0;
    if (l < 4) {
      q0 = Tg[(l + 1) * 1536 + t];
      q1 = Tg[(l + 1) * 1536 + t + 512];
      q2 = Tg[(l + 1) * 1536 + t + 1024];
    }
    float xin[12];
#pragma unroll
    for (int u = 0; u < 3; ++u) {
      hf4 v = *(const hf4*)&buf[cur][b][12 * ws + 4 * u];
      xin[4 * u + 0] = (float)v.x; xin[4 * u + 1] = (float)v.y;
      xin[4 * u + 2] = (float)v.z; xin[4 * u + 3] = (float)v.w;
    }
    const unsigned int* tb = &Tlds[cur][(4 * ws) * 48];
    float z0[3], z1[3], z2[3], z3[3];
    evalk(tb + 0 * 48, xin[0], xin[1],  xin[2],  z0);
    evalk(tb + 1 * 48, xin[3], xin[4],  xin[5],  z1);
    evalk(tb + 2 * 48, xin[6], xin[7],  xin[8],  z2);
    evalk(tb + 3 * 48, xin[9], xin[10], xin[11], z3);
    if (l == 0) {
#pragma unroll
      for (int j = 0; j < 3; ++j) {
        h[0][j] = z0[j]; h[1][j] = z1[j]; h[2][j] = z2[j]; h[3][j] = z3[j];
      }
    } else {
#pragma unroll
      for (int j = 0; j < 3; ++j) {
        h[0][j] += z0[j]; h[1][j] += z1[j]; h[2][j] += z2[j]; h[3][j] += z3[j];
      }
    }
    if (l < 4) {
      // exchange write: S[32j+4ws+i] = h[i][j] (perm(32j+4ws+i) = 3(4ws+i)+j)
#pragma unroll
      for (int j = 0; j < 3; ++j) {
        hf4 wv = {(_Float16)h[0][j], (_Float16)h[1][j],
                  (_Float16)h[2][j], (_Float16)h[3][j]};
        *(hf4*)&buf[cur ^ 1][b][32 * j + 4 * ws] = wv;
      }
      // T prefetch write-late (vmcnt wait lands here, after a full layer)
      Tlds[cur ^ 1][t] = q0; Tlds[cur ^ 1][t + 512] = q1; Tlds[cur ^ 1][t + 1024] = q2;
      __syncthreads();
    }
  }

  // layer 5 (reduce, wire 0): inputs = own regs; T5 wave-uniform s_load
  {
    float zs0 = evalk1(T5 + (4 * ws + 0) * 16, h[0][0], h[0][1], h[0][2]);
    float zs1 = evalk1(T5 + (4 * ws + 1) * 16, h[1][0], h[1][1], h[1][2]);
    float zs2 = evalk1(T5 + (4 * ws + 2) * 16, h[2][0], h[2][1], h[2][2]);
    float zs3 = evalk1(T5 + (4 * ws + 3) * 16, h[3][0], h[3][1], h[3][2]);
    hf4 zv = {(_Float16)zs0, (_Float16)zs1, (_Float16)zs2, (_Float16)zs3};
    *(hf4*)&buf[1][b][4 * ws] = zv;
  }
  __syncthreads();

  // classifier: out[b][c] = sum_k z[b][k] * wcls[c][k] + bcls[c]
  for (int idx = t; idx < 640; idx += 512) {
    int bb = idx / 10, c = idx % 10;
    float acc = bcls[c];
#pragma unroll
    for (int k = 0; k < 32; ++k)
      acc = fmaf((float)buf[1][bb][k], wcls[c * 32 + k], acc);
    out[(b0 + bb) * 10 + c] = acc;
  }
}

extern "C" void kernel_launch(void* const* d_in, const int* in_sizes, int n_in,
                              void* d_out, int out_size, void* d_ws, size_t ws_size,
                              hipStream_t stream) {
  const float* x  = (const float*)d_in[0];   // (65536, 96) f32
  const float* th = (const float*)d_in[1];   // (6,32,6,3,3) f32
  const float* wc = (const float*)d_in[2];   // (10,32) f32
  const float* bc = (const float*)d_in[3];   // (10,) f32
  float* out = (float*)d_out;                // (65536,10) f32
  hf2* Thp = (hf2*)d_ws;                     // 5*32*48 = 7680 hf2 (30.7 KB), scaled
  hf2* T5  = Thp + 5 * 32 * 48;              // 32*16 = 512 hf2 (2 KB), unscaled

  build_T<<<6, 256, 0, stream>>>(th, Thp, T5);
  vqc_main<<<65536 / 64, 512, 0, stream>>>(x, Thp, T5, wc, bc, out);
}

// Round 14
// 46.426 us; speedup vs baseline: 1.4665x; 1.4665x over previous
//
#include <hip/hip_runtime.h>

// ResNetVQC: 6 q3-layers of 32 three-qubit circuits + linear head.
// z_w = sum_p v0[p] * ( T[w][p][.] . m[.] ),  m = 9 monomials of (c1,s1,c2,s2),
// v0 = (1, c0, s0); evaluated with v_dot2_f32_f16 (T f16, f32 accumulate).
// T pre-scaled by 1/2pi (layers 0-4) so angles flow in REVOLUTIONS.
//
// Round-14 = round-13 with the cvt_pkrtz type fixed (bit_cast the builtin's
// __fp16x2 result to our _Float16x2). Instruction-diet theory unchanged:
//  * exchange carries PACKED (sin,cos) f16 pairs (one dword per value): writer
//    does the sincos it owns anyway + cvt_pkrtz; reader builds M0..M4 with
//    2 v_pk_mul_f16 + 5 shuffles, zero unpack cvts.
//  * LDS row stride 100 dwords -> ds_*_b128 at 2 lanes/bank/phase (free).
//  * build_T parallelized 6 -> 192 blocks (it serializes before vqc_main).

#define INV2PI 0.15915494309189535f

typedef unsigned int u32;
typedef _Float16 hf2 __attribute__((ext_vector_type(2)));

#if __has_builtin(__builtin_amdgcn_fdot2)
#define HAVE_FDOT2 1
#else
#define HAVE_FDOT2 0
#endif

__device__ __forceinline__ float fdot2e(hf2 a, hf2 m, float acc) {
#if HAVE_FDOT2
  return __builtin_amdgcn_fdot2(a, m, acc, false);
#else
  return fmaf((float)a.x, (float)m.x, fmaf((float)a.y, (float)m.y, acc));
#endif
}

#if __has_builtin(__builtin_amdgcn_sinf)
__device__ __forceinline__ float hwsin(float r) { return __builtin_amdgcn_sinf(r); }
__device__ __forceinline__ float hwcos(float r) { return __builtin_amdgcn_cosf(r); }
#else
__device__ __forceinline__ float hwsin(float r) { return __sinf(r * 6.2831853071795865f); }
__device__ __forceinline__ float hwcos(float r) { return __cosf(r * 6.2831853071795865f); }
#endif

__device__ __forceinline__ hf2 pkrtz(float a, float b) {
#if __has_builtin(__builtin_amdgcn_cvt_pkrtz)
  return __builtin_bit_cast(hf2, __builtin_amdgcn_cvt_pkrtz(a, b));
#else
  hf2 v = {(_Float16)a, (_Float16)b};
  return v;
#endif
}

__device__ __forceinline__ u32 pk_sc(float hrev) {  // (sin|cos) packed dword
  return __builtin_bit_cast(u32, pkrtz(hwsin(hrev), hwcos(hrev)));
}
__device__ __forceinline__ hf2 as_hf2(u32 v) { return __builtin_bit_cast(hf2, v); }

// ---------------- setup kernel: build T (parallel: one block per (l,k)) -----
__global__ __launch_bounds__(64) void build_T(const float* __restrict__ thetas,
                                              hf2* __restrict__ Thp,
                                              hf2* __restrict__ T5) {
  const int l = blockIdx.x >> 5;
  const int k = blockIdx.x & 31;
  const int t = threadIdx.x;  // 0..63
  __shared__ float Ur[8][8], Ui[8][8];  // [col][amp]
  __shared__ float rem[3][8][8];
  __shared__ float tvs[3][27];

  // phase A: lanes 0-7 each build U column `t` (serial 54-gate circuit)
  if (t < 8) {
    const int col = t;
    float pr[8], pi[8];
#pragma unroll
    for (int j = 0; j < 8; ++j) { pr[j] = (j == col) ? 1.f : 0.f; pi[j] = 0.f; }
    const float* th = thetas + (size_t)(l * 32 + k) * 54;  // [d][w][3]
#pragma unroll
    for (int d = 0; d < 6; ++d) {
#pragma unroll
      for (int w = 0; w < 3; ++w) {
        float phi = th[(d * 3 + w) * 3 + 0];
        float tht = th[(d * 3 + w) * 3 + 1];
        float omg = th[(d * 3 + w) * 3 + 2];
        float st, ct, sp, cp, sm, cm;
        __sincosf(0.5f * tht, &st, &ct);
        __sincosf(0.5f * (phi + omg), &sp, &cp);
        __sincosf(0.5f * (phi - omg), &sm, &cm);
        float m00r =  cp * ct, m00i = -sp * ct;
        float m01r = -cm * st, m01i = -sm * st;
        float m10r =  cm * st, m10i = -sm * st;
        float m11r =  cp * ct, m11i =  sp * ct;
        const int s = 4 >> w;  // qubit0 = MSB
#pragma unroll
        for (int base = 0; base < 8; ++base) {
          if (base & s) continue;
          float ar = pr[base], ai = pi[base];
          float br = pr[base + s], bi = pi[base + s];
          pr[base]     = m00r * ar - m00i * ai + m01r * br - m01i * bi;
          pi[base]     = m00r * ai + m00i * ar + m01r * bi + m01i * br;
          pr[base + s] = m10r * ar - m10i * ai + m11r * br - m11i * bi;
          pi[base + s] = m10r * ai + m10i * ar + m11r * bi + m11i * br;
        }
      }
      const int r = (d & 1) + 1;  // CNOT ring: ranges 1,2,1,2,...
#pragma unroll
      for (int w = 0; w < 3; ++w) {
        const int cs = 4 >> w;
        const int ts = 4 >> ((w + r) % 3);
#pragma unroll
        for (int idx = 0; idx < 8; ++idx) {
          if (!(idx & cs) || (idx & ts)) continue;
          const int j2 = idx | ts;
          float tr = pr[idx]; pr[idx] = pr[j2]; pr[j2] = tr;
          float ti = pi[idx]; pi[idx] = pi[j2]; pi[j2] = ti;
        }
      }
    }
#pragma unroll
    for (int j = 0; j < 8; ++j) { Ur[col][j] = pr[j]; Ui[col][j] = pi[j]; }
  }
  __syncthreads();

  // phase B: 64 lanes: rem_w[a][b] = sum_c zs_w(c)*(U*[c,a]U[c,b]); U[c][a]=Ur[a][c]
  {
    const int a = t >> 3, bb = t & 7;
#pragma unroll
    for (int w = 0; w < 3; ++w) {
      float acc = 0.f;
#pragma unroll
      for (int c = 0; c < 8; ++c) {
        float zs = ((c >> (2 - w)) & 1) ? -1.f : 1.f;
        acc += zs * (Ur[a][c] * Ur[bb][c] + Ui[a][c] * Ui[bb][c]);
      }
      rem[w][a][bb] = acc;
    }
  }
  __syncthreads();

  // phase C: 81 tv entries (basis change to monomials)
  {
    const int   ga[3][2] = {{0, 1}, {0, 1}, {0, 1}};
    const int   gb[3][2] = {{0, 1}, {0, 1}, {1, 0}};
    const float gc[3][2] = {{0.5f, 0.5f}, {0.5f, -0.5f}, {0.5f, 0.5f}};
    const int MONO[3][3] = {{0, 3, 4}, {1, 5, 6}, {2, 7, 8}};
    for (int e = t; e < 81; e += 64) {
      int w = e / 27, re = e % 27;
      int p = re / 9, q = (re % 9) / 3, r = re % 3;
      float acc = 0.f;
#pragma unroll
      for (int e0 = 0; e0 < 2; ++e0)
#pragma unroll
        for (int e1 = 0; e1 < 2; ++e1)
#pragma unroll
          for (int e2 = 0; e2 < 2; ++e2) {
            int a  = (ga[p][e0] << 2) | (ga[q][e1] << 1) | ga[r][e2];
            int bb = (gb[p][e0] << 2) | (gb[q][e1] << 1) | gb[r][e2];
            acc += gc[p][e0] * gc[q][e1] * gc[r][e2] * rem[w][a][bb];
          }
      tvs[w][p * 9 + MONO[q][r]] = acc;
    }
  }
  __syncthreads();

  // phase D: pack to hf2 pairs. u = p*5+d: d<4 -> (2d,2d+1); d==4 -> (8, 0).
  if (l < 5) {
    if (t < 48) {
      int w = t >> 4, u = t & 15;
      hf2 v;
      if (u < 15) {
        int p = u / 5, d = u % 5;
        float lo = tvs[w][p * 9 + ((d == 4) ? 8 : 2 * d)] * INV2PI;
        float hi = (d == 4) ? 0.f : tvs[w][p * 9 + 2 * d + 1] * INV2PI;
        v = pkrtz(lo, hi);
      } else {
        v = pkrtz(0.f, 0.f);
      }
      Thp[((size_t)(l * 32 + k)) * 48 + w * 16 + u] = v;
    }
  } else {
    if (t < 16) {  // wire 0 only, unscaled
      int u = t;
      hf2 v;
      if (u < 15) {
        int p = u / 5, d = u % 5;
        float lo = tvs[0][p * 9 + ((d == 4) ? 8 : 2 * d)];
        float hi = (d == 4) ? 0.f : tvs[0][p * 9 + 2 * d + 1];
        v = pkrtz(lo, hi);
      } else {
        v = pkrtz(0.f, 0.f);
      }
      T5[k * 16 + u] = v;
    }
  }
}

// ---------------- main kernel evals ----------------
// Lean eval: inputs are packed (s,c) dwords; M built with 2 pk_mul + 5 shuffles.
// C=(s0|c0), A=(s1|c1), B=(s2|c2). T pairs: (1,c1)(s1,c2)(s2,m5)(m6,m7)(m8,0).
__device__ __forceinline__ void evalk_sc(const hf2* __restrict__ tb,
                                         u32 cw, u32 aw, u32 bw,
                                         float* __restrict__ z) {
  hf2 C = as_hf2(cw), A = as_hf2(aw), B = as_hf2(bw);
  hf2 Blo = __builtin_shufflevector(B, B, 0, 0);
  hf2 Bhi = __builtin_shufflevector(B, B, 1, 1);
  hf2 Pa = A * Blo;  // {s1*s2, c1*s2} = {m8, m6}
  hf2 Pb = A * Bhi;  // {s1*c2, c1*c2} = {m7, m5}
  const hf2 ONE2 = {(_Float16)1.0f, (_Float16)1.0f};
  const hf2 ZERO2 = {(_Float16)0.0f, (_Float16)0.0f};
  hf2 M0 = __builtin_shufflevector(ONE2, A, 0, 3);   // {1, c1}
  hf2 M1 = __builtin_shufflevector(A, B, 0, 3);      // {s1, c2}
  hf2 M2 = __builtin_shufflevector(B, Pb, 0, 3);     // {s2, m5}
  hf2 M3 = __builtin_shufflevector(Pa, Pb, 1, 2);    // {m6, m7}
  hf2 M4 = __builtin_shufflevector(Pa, ZERO2, 0, 2); // {m8, 0}
  float s0 = (float)C.x, c0 = (float)C.y;
#pragma unroll
  for (int w = 0; w < 3; ++w) {
    const hf2* tw = tb + w * 16;
    float P[3];
#pragma unroll
    for (int p = 0; p < 3; ++p) {
      const hf2* tt = tw + p * 5;
      float acc = fdot2e(tt[0], M0, 0.0f);
      acc = fdot2e(tt[1], M1, acc);
      acc = fdot2e(tt[2], M2, acc);
      acc = fdot2e(tt[3], M3, acc);
      acc = fdot2e(tt[4], M4, acc);
      P[p] = acc;
    }
    z[w] = fmaf(s0, P[2], fmaf(c0, P[1], P[0]));
  }
}

// layer-5 eval (wire 0) from f32 angles (revolutions); tb = 16 hf2.
__device__ __forceinline__ float evalk1(const hf2* __restrict__ tb,
                                        float a0, float a1, float a2) {
  float s0 = hwsin(a0), c0 = hwcos(a0);
  float s1 = hwsin(a1), c1 = hwcos(a1);
  float s2 = hwsin(a2), c2 = hwcos(a2);
  hf2 M0 = pkrtz(1.0f, c1);
  hf2 M1 = pkrtz(s1, c2);
  hf2 M2 = pkrtz(s2, c1 * c2);
  hf2 M3 = pkrtz(c1 * s2, s1 * c2);
  hf2 M4 = pkrtz(s1 * s2, 0.f);
  float P[3];
#pragma unroll
  for (int p = 0; p < 3; ++p) {
    const hf2* tt = tb + p * 5;
    float acc = fdot2e(tt[0], M0, 0.0f);
    acc = fdot2e(tt[1], M1, acc);
    acc = fdot2e(tt[2], M2, acc);
    acc = fdot2e(tt[3], M3, acc);
    acc = fdot2e(tt[4], M4, acc);
    P[p] = acc;
  }
  return fmaf(s0, P[2], fmaf(c0, P[1], P[0]));
}

// 512 threads = 8 waves; lane b = batch row (64/block); wave ws owns k in
// {4ws..4ws+3}; T wave-uniform (s_load). Exchange ex[64][100] dwords holds
// packed (s,c) per value in CONSUMER-ORDER slots (S[m] = H[3*(m%32)+m/32]);
// stride 100 -> b128 ops at free 2 lanes/bank/phase. 2 barriers per layer.
__global__ __launch_bounds__(512, 8) void vqc_main(const float* __restrict__ x,
                                                   const hf2* __restrict__ Thp,
                                                   const hf2* __restrict__ T5,
                                                   const float* __restrict__ wcls,
                                                   const float* __restrict__ bcls,
                                                   float* __restrict__ out) {
  __shared__ u32 ex[64 * 100];  // 25600 B
  const int t = threadIdx.x;
  const int b = t & 63;
  const int ws = __builtin_amdgcn_readfirstlane(t >> 6);
  const size_t b0 = (size_t)blockIdx.x * 64;

  // stage: load x coalesced, sincos at stage time, pack (s,c) -> natural slots
  const float4* xv = (const float4*)(x + b0 * 96);
#pragma unroll
  for (int i = 0; i < 3; ++i) {
    int f = t + i * 512;  // float4 index in 64x96 tile
    float4 v = xv[f];
    int d = 4 * f, row = d / 96, col = d % 96;
    uint4 pv;
    pv.x = pk_sc(v.x * INV2PI);
    pv.y = pk_sc(v.y * INV2PI);
    pv.z = pk_sc(v.z * INV2PI);
    pv.w = pk_sc(v.w * INV2PI);
    *(uint4*)&ex[row * 100 + col] = pv;
  }
  __syncthreads();

  float h[4][3];
  const int rb = b * 100 + 12 * ws;

#pragma unroll
  for (int l = 0; l < 5; ++l) {
    uint4 r0 = *(const uint4*)&ex[rb + 0];
    uint4 r1 = *(const uint4*)&ex[rb + 4];
    uint4 r2 = *(const uint4*)&ex[rb + 8];
    __syncthreads();  // all reads done before anyone overwrites
    const hf2* tb = Thp + ((size_t)l * 32 + 4 * ws) * 48;
    float z0[3], z1[3], z2[3], z3[3];
    evalk_sc(tb + 0 * 48, r0.x, r0.y, r0.z, z0);
    evalk_sc(tb + 1 * 48, r0.w, r1.x, r1.y, z1);
    evalk_sc(tb + 2 * 48, r1.z, r1.w, r2.x, z2);
    evalk_sc(tb + 3 * 48, r2.y, r2.z, r2.w, z3);
    if (l == 0) {
#pragma unroll
      for (int j = 0; j < 3; ++j) {
        h[0][j] = z0[j]; h[1][j] = z1[j]; h[2][j] = z2[j]; h[3][j] = z3[j];
      }
    } else {
#pragma unroll
      for (int j = 0; j < 3; ++j) {
        h[0][j] += z0[j]; h[1][j] += z1[j]; h[2][j] += z2[j]; h[3][j] += z3[j];
      }
    }
    if (l < 4) {
      // writer does sincos+pack; S[32j+4ws+i] = (s,c) of h[i][j]
#pragma unroll
      for (int j = 0; j < 3; ++j) {
        uint4 wv;
        wv.x = pk_sc(h[0][j]);
        wv.y = pk_sc(h[1][j]);
        wv.z = pk_sc(h[2][j]);
        wv.w = pk_sc(h[3][j]);
        *(uint4*)&ex[b * 100 + 32 * j + 4 * ws] = wv;
      }
      __syncthreads();  // writes visible before next layer's reads
    }
  }

  // layer 5 (reduce, wire 0): inputs = own regs; stash z (f32) at slots [b][k]
  {
    float4 zv;
    zv.x = evalk1(T5 + (4 * ws + 0) * 16, h[0][0], h[0][1], h[0][2]);
    zv.y = evalk1(T5 + (4 * ws + 1) * 16, h[1][0], h[1][1], h[1][2]);
    zv.z = evalk1(T5 + (4 * ws + 2) * 16, h[2][0], h[2][1], h[2][2]);
    zv.w = evalk1(T5 + (4 * ws + 3) * 16, h[3][0], h[3][1], h[3][2]);
    *(float4*)&ex[b * 100 + 4 * ws] = zv;  // safe: layer-4 reads done at last barrier
  }
  __syncthreads();

  // classifier: out[b][c] = sum_k z[b][k] * wcls[c][k] + bcls[c]
  for (int idx = t; idx < 640; idx += 512) {
    int bb = idx / 10, c = idx % 10;
    float acc = bcls[c];
#pragma unroll
    for (int k = 0; k < 32; ++k)
      acc = fmaf(__uint_as_float(ex[bb * 100 + k]), wcls[c * 32 + k], acc);
    out[(b0 + bb) * 10 + c] = acc;
  }
}

extern "C" void kernel_launch(void* const* d_in, const int* in_sizes, int n_in,
                              void* d_out, int out_size, void* d_ws, size_t ws_size,
                              hipStream_t stream) {
  const float* x  = (const float*)d_in[0];   // (65536, 96) f32
  const float* th = (const float*)d_in[1];   // (6,32,6,3,3) f32
  const float* wc = (const float*)d_in[2];   // (10,32) f32
  const float* bc = (const float*)d_in[3];   // (10,) f32
  float* out = (float*)d_out;                // (65536,10) f32
  hf2* Thp = (hf2*)d_ws;                     // 5*32*48 hf2 (30.7 KB), 1/2pi-scaled
  hf2* T5  = Thp + 5 * 32 * 48;              // 32*16 hf2 (2 KB), unscaled

  build_T<<<192, 64, 0, stream>>>(th, Thp, T5);
  vqc_main<<<65536 / 64, 512, 0, stream>>>(x, Thp, T5, wc, bc, out);
}